// Round 10
// baseline (431.468 us; speedup 1.0000x reference)
//
#include <hip/hip_runtime.h>

typedef unsigned short ushort_t;
typedef unsigned int uint_t;

#define NN 20000
#define EE 320000
#define CC 32
#define NEL 10
#define GG 64
#define TTT 1000
#define NBB 8
#define HIDD 64
#define NPB 4           // nodes per block in k_flay (NN = 5000*4)
#define MAXDEG 64       // safety clamp (deg ~ Poisson(16); P(>64) ~ 1e-19)

typedef __attribute__((ext_vector_type(8))) short bf16x8;
typedef __attribute__((ext_vector_type(4))) float f32x4;

__device__ __forceinline__ float bits2f(uint_t b) { union { uint_t u; float f; } v; v.u = b; return v.f; }
__device__ __forceinline__ ushort_t f2b(float f) {
  union { float f; uint_t u; } v; v.f = f;
  uint_t r = (v.u + 0x7fffu + ((v.u >> 16) & 1u)) >> 16;
  return (ushort_t)r;
}
__device__ __forceinline__ uint_t pk(float a, float b) {
  return (uint_t)f2b(a) | ((uint_t)f2b(b) << 16);
}
__device__ __forceinline__ float lo16(uint_t u) { return bits2f(u << 16); }
__device__ __forceinline__ float hi16(uint_t u) { return bits2f(u & 0xffff0000u); }

// ---------- K1: block0 = receiver histogram (LDS, packed u16) + scan;
//             blocks 1..20 = node prep -------------------------------------
__global__ __launch_bounds__(1024) void k_scanprep(
    const float* __restrict__ positions, const float* __restrict__ node_attrs,
    const float* __restrict__ eps, const float* __restrict__ alpha_bar,
    const float* __restrict__ W_embed, const float* __restrict__ W_sc,
    const int* __restrict__ batch, const int* __restrict__ tarr,
    const int* __restrict__ ei,
    float* __restrict__ pos_noisy, float* __restrict__ scalA,
    float* __restrict__ sc_skip, float* __restrict__ pred,
    int* __restrict__ offs, int* __restrict__ cursor,
    float* __restrict__ lnum, float* __restrict__ lcnt, int* __restrict__ ticket)
{
  __shared__ uint_t hist[NN / 2];   // 40 KB, two u16 counts per dword
  __shared__ int wsums[16];
  __shared__ int woffs[16];
  int tid = threadIdx.x;
  if (blockIdx.x == 0) {
    int lane = tid & 63, wv = tid >> 6;
    if (tid < GG) { lnum[tid] = 0.0f; lcnt[tid] = 0.0f; }
    if (tid == 64) *ticket = 0;
    for (int i = tid; i < NN / 2; i += 1024) hist[i] = 0u;
    __syncthreads();
#pragma unroll 4
    for (int e = tid; e < EE; e += 1024) {
      int r = ei[EE + e];
      atomicAdd(&hist[r >> 1], 1u << ((r & 1) * 16));
    }
    __syncthreads();
    int base = tid * 20;
    int loc[20];
    int s = 0;
#pragma unroll
    for (int j = 0; j < 20; ++j) {
      int idx = base + j;
      int v = 0;
      if (idx < NN) v = (int)((hist[idx >> 1] >> ((idx & 1) * 16)) & 0xffffu);
      loc[j] = s; s += v;
    }
    int inc = s;
    for (int o = 1; o < 64; o <<= 1) {
      int v = __shfl_up(inc, o, 64);
      if (lane >= o) inc += v;
    }
    if (lane == 63) wsums[wv] = inc;
    __syncthreads();
    if (wv == 0 && lane < 16) {
      int v = wsums[lane];
      int i2 = v;
      for (int o = 1; o < 16; o <<= 1) {
        int vv = __shfl_up(i2, o, 16);
        if (lane >= o) i2 += vv;
      }
      woffs[lane] = i2 - v;
    }
    __syncthreads();
    int texcl = woffs[wv] + (inc - s);
#pragma unroll
    for (int j = 0; j < 20; ++j) {
      int idx = base + j;
      if (idx < NN) { int v = texcl + loc[j]; offs[idx] = v; cursor[idx] = v; }
    }
    if (tid == 1023) offs[NN] = EE;
  } else {
    int n = (blockIdx.x - 1) * 1024 + tid;
    if (n >= NN) return;
    int g = batch[n];
    int tn = tarr[g];
    float ab = alpha_bar[tn];
    float sa = sqrtf(ab), sb = sqrtf(fmaxf(1.0f - ab, 0.0f));
#pragma unroll
    for (int j = 0; j < 3; ++j)
      pos_noisy[n * 3 + j] = sa * positions[n * 3 + j] + sb * eps[n * 13 + 10 + j];
    float an[10];
#pragma unroll
    for (int j = 0; j < 10; ++j)
      an[j] = sa * 0.25f * node_attrs[n * 10 + j] + sb * eps[n * 13 + j];
    float tf = (float)tn * (1.0f / (float)TTT);
    for (int d = 0; d < CC; ++d) {
      float h = tf * W_embed[10 * CC + d];
      float sk = 0.0f;
#pragma unroll
      for (int j = 0; j < 10; ++j) {
        h = fmaf(an[j], W_embed[j * CC + d], h);
        sk = fmaf(an[j], W_sc[j * CC + d], sk);
      }
      scalA[n * CC + d] = h;
      sc_skip[n * CC + d] = sk;
    }
#pragma unroll
    for (int j = 0; j < 13; ++j) pred[n * 13 + j] = 0.0f;
  }
}

// ---------------- K2: edge geometry, written into receiver-sorted slots ------
__global__ __launch_bounds__(256) void k_edge2(
    const float* __restrict__ pos_noisy, const float* __restrict__ shifts,
    const int* __restrict__ ei, int* __restrict__ cursor,
    ushort_t* __restrict__ Ys, ushort_t* __restrict__ efs, int* __restrict__ snds)
{
  int e = blockIdx.x * 256 + threadIdx.x;  // EE exact
  int snd = ei[e], rcv = ei[EE + e];
  float vx = pos_noisy[rcv * 3 + 0] - pos_noisy[snd * 3 + 0] + shifts[e * 3 + 0];
  float vy = pos_noisy[rcv * 3 + 1] - pos_noisy[snd * 3 + 1] + shifts[e * 3 + 1];
  float vz = pos_noisy[rcv * 3 + 2] - pos_noisy[snd * 3 + 2] + shifts[e * 3 + 2];
  float r2 = vx * vx + vy * vy + vz * vz + 1e-12f;
  float r = sqrtf(r2);
  float inv = 1.0f / r;
  float x = vx * inv, y = vy * inv, z = vz * inv;

  const float s3 = 1.7320508075688772f, s15 = 3.872983346207417f, s5 = 2.23606797749979f;
  const float s105 = 10.246950765959598f, s7 = 2.6457513110645907f;
  const float s35_8 = 2.091650066335189f, s21_8 = 1.6201851746019651f;
  float yv[16];
  yv[0] = 1.0f;
  yv[1] = s3 * x; yv[2] = s3 * y; yv[3] = s3 * z;
  yv[4] = s15 * x * y;
  yv[5] = s15 * y * z;
  yv[6] = 0.5f * s5 * (3.0f * z * z - 1.0f);
  yv[7] = s15 * x * z;
  yv[8] = 0.5f * s15 * (x * x - y * y);
  yv[9] = s35_8 * y * (3.0f * x * x - y * y);
  yv[10] = s105 * x * y * z;
  yv[11] = s21_8 * y * (5.0f * z * z - 1.0f);
  yv[12] = 0.5f * s7 * (5.0f * z * z * z - 3.0f * z);
  yv[13] = s21_8 * x * (5.0f * z * z - 1.0f);
  yv[14] = 0.5f * s105 * z * (x * x - y * y);
  yv[15] = s35_8 * x * (x * x - 3.0f * y * y);

  // radial embed: sqrt(2/5) * sin(n*pi*rc/5)/rc * poly_cutoff(r/5)
  float rc = fmaxf(r, 1e-9f);
  float pref = 0.6324555320336759f / rc;
  float th = 0.6283185307179586f * rc;
  float s1 = __sinf(th), c1 = __cosf(th);
  float xr = r * 0.2f;
  float fcut = 0.0f;
  if (xr < 1.0f) {
    float x2 = xr * xr, x3 = x2 * xr;
    float x6 = x3 * x3, x7 = x6 * xr, x8 = x7 * xr;
    fcut = 1.0f - 28.0f * x6 + 48.0f * x7 - 21.0f * x8;
  }
  float efv[8];
  float sp = 0.0f, scur = s1, c2 = 2.0f * c1;
#pragma unroll
  for (int b = 0; b < 8; ++b) {
    efv[b] = pref * scur * fcut;
    float nx = c2 * scur - sp;   // sin((n+1)th) = 2cos(th)sin(n th) - sin((n-1)th)
    sp = scur; scur = nx;
  }

  int slot = atomicAdd(&cursor[rcv], 1);
  snds[slot] = snd;
  uint4* Y4 = (uint4*)Ys;
  Y4[(size_t)slot * 2 + 0] = make_uint4(pk(yv[0], yv[1]), pk(yv[2], yv[3]),
                                        pk(yv[4], yv[5]), pk(yv[6], yv[7]));
  Y4[(size_t)slot * 2 + 1] = make_uint4(pk(yv[8], yv[9]), pk(yv[10], yv[11]),
                                        pk(yv[12], yv[13]), pk(yv[14], yv[15]));
  ((uint4*)efs)[slot] = make_uint4(pk(efv[0], efv[1]), pk(efv[2], efv[3]),
                                   pk(efv[4], efv[5]), pk(efv[6], efv[7]));
}

// ---------------- K3: fused layer v3 -----------------------------------------
// Wave = node. Per 16-edge tile: h1 in regs; MFMA with A=W2^T frags, B=h1
// (D = [col][edge]) -> one b64 LDS write per n-tile; Y staged to LDS; agg loop
// is pure LDS+VALU. LDS: [0,18432) w2t (reused as lagg+lf after barrier);
// [18432,20480) w1s f32; [20480,37376) rwt[4][16][132]; [37376,39424) ysh[4][16][16].
__global__ __launch_bounds__(256) void k_flay(
    const ushort_t* __restrict__ efs, const ushort_t* __restrict__ Ys,
    const int* __restrict__ snds, const int* __restrict__ offs,
    const float* __restrict__ W_r1, const float* __restrict__ W_r2,
    const float* __restrict__ scal_in, float* __restrict__ scal_out,
    const float* __restrict__ W_mix, const float* __restrict__ W_prod,
    const float* __restrict__ W_ro_s, const float* __restrict__ W_ro_v,
    const float* __restrict__ sc_skip, float* __restrict__ pred, int layer)
{
  __shared__ __align__(16) char lds[39424];
  ushort_t (*w2t)[72] = (ushort_t(*)[72])lds;              // phase A
  float (*lagg)[CC][16] = (float(*)[CC][16])lds;           // phase C (aliases w2t)
  float (*lf)[CC][4] = (float(*)[CC][4])(lds + 8192);      // phase C
  float* w1s = (float*)(lds + 18432);                      // persistent

  int tid = threadIdx.x;
  int w = tid >> 6, lane = tid & 63;
  ushort_t (*rwt)[132] = (ushort_t(*)[132])(lds + 20480 + w * 4224);
  ushort_t (*ysh)[16] = (ushort_t(*)[16])(lds + 37376 + w * 512);

  int n0 = blockIdx.x * NPB;
  const float* W1g = W_r1 + layer * NBB * HIDD;
  const float* W2g = W_r2 + layer * HIDD * 128;

  for (int idx = tid; idx < HIDD * 128; idx += 256) {
    int k = idx >> 7, n = idx & 127;
    w2t[n][k] = f2b(W2g[idx]);
  }
  for (int idx = tid; idx < NBB * HIDD; idx += 256) w1s[idx] = W1g[idx];
  __syncthreads();

  int c16 = lane & 15, quad = lane >> 4;
  bf16x8 bfr[16];   // A-operand frags: A[m=col=c16][k] = W2^T
#pragma unroll
  for (int nt = 0; nt < 8; ++nt)
#pragma unroll
    for (int kt = 0; kt < 2; ++kt)
      bfr[nt * 2 + kt] = *(const bf16x8*)&w2t[nt * 16 + c16][kt * 32 + quad * 8];

  int oj = offs[n0 + w];
  int dj = min(offs[n0 + w + 1] - oj, MAXDEG);

  int cA = lane >> 1, kh = lane & 1, kb = kh * 8;
  float acc0 = 0, acc1 = 0, acc2 = 0, acc3 = 0, acc4 = 0, acc5 = 0, acc6 = 0, acc7 = 0;
  const uint4* Y4 = (const uint4*)Ys;

  for (int kbase = 0; kbase < dj; kbase += 16) {
    // ---- stage this tile's Y into LDS (lanes<32; zero for pad edges)
    if (lane < 32) {
      int et = lane >> 1, half = lane & 1;
      int ke = kbase + et;
      uint4 yq = make_uint4(0, 0, 0, 0);
      if (ke < dj) yq = Y4[(size_t)(oj + ke) * 2 + half];
      *(uint4*)&ysh[et][half * 8] = yq;
    }
    // ---- h1 B-fragments in registers (lane covers edge kbase+c16, k=quad*8..)
    bf16x8 a0, a1;
    {
      int kc = kbase + c16;
      float ef8[8] = {0, 0, 0, 0, 0, 0, 0, 0};
      if (kc < dj) {
        uint4 q = ((const uint4*)efs)[(size_t)(oj + kc)];
        ef8[0] = lo16(q.x); ef8[1] = hi16(q.x); ef8[2] = lo16(q.y); ef8[3] = hi16(q.y);
        ef8[4] = lo16(q.z); ef8[5] = hi16(q.z); ef8[6] = lo16(q.w); ef8[7] = hi16(q.w);
      }
      float h0[8] = {0, 0, 0, 0, 0, 0, 0, 0};
      float h1v[8] = {0, 0, 0, 0, 0, 0, 0, 0};
#pragma unroll
      for (int b = 0; b < 8; ++b) {
        const float* wb = &w1s[b * HIDD];
        float4 wa = *(const float4*)&wb[quad * 8];
        float4 wbv = *(const float4*)&wb[quad * 8 + 4];
        float4 wc = *(const float4*)&wb[32 + quad * 8];
        float4 wd = *(const float4*)&wb[32 + quad * 8 + 4];
        float e = ef8[b];
        h0[0] = fmaf(e, wa.x, h0[0]); h0[1] = fmaf(e, wa.y, h0[1]);
        h0[2] = fmaf(e, wa.z, h0[2]); h0[3] = fmaf(e, wa.w, h0[3]);
        h0[4] = fmaf(e, wbv.x, h0[4]); h0[5] = fmaf(e, wbv.y, h0[5]);
        h0[6] = fmaf(e, wbv.z, h0[6]); h0[7] = fmaf(e, wbv.w, h0[7]);
        h1v[0] = fmaf(e, wc.x, h1v[0]); h1v[1] = fmaf(e, wc.y, h1v[1]);
        h1v[2] = fmaf(e, wc.z, h1v[2]); h1v[3] = fmaf(e, wc.w, h1v[3]);
        h1v[4] = fmaf(e, wd.x, h1v[4]); h1v[5] = fmaf(e, wd.y, h1v[5]);
        h1v[6] = fmaf(e, wd.z, h1v[6]); h1v[7] = fmaf(e, wd.w, h1v[7]);
      }
#pragma unroll
      for (int jj = 0; jj < 8; ++jj) {
        float v0 = h0[jj];  v0 = v0 / (1.0f + __expf(-v0));
        float v1 = h1v[jj]; v1 = v1 / (1.0f + __expf(-v1));
        a0[jj] = (short)f2b(v0);
        a1[jj] = (short)f2b(v1);
      }
    }
    // ---- one sender per lane; hoist 8 independent ss loads (chan = 4nt+quad)
    int kc = kbase + c16;
    int snd_c = snds[oj + ((kc < dj) ? kc : (dj - 1))];
    float ssv[8];
    {
      const float* sb = scal_in + (size_t)snd_c * CC + quad;
#pragma unroll
      for (int nt = 0; nt < 8; ++nt) ssv[nt] = sb[nt * 4];
    }
    // ---- MFMA (D=[col][edge]) + ss epilogue -> one b64 LDS write per n-tile
#pragma unroll
    for (int nt = 0; nt < 8; ++nt) {
      f32x4 acc = {0.0f, 0.0f, 0.0f, 0.0f};
      acc = __builtin_amdgcn_mfma_f32_16x16x32_bf16(bfr[nt * 2 + 0], a0, acc, 0, 0, 0);
      acc = __builtin_amdgcn_mfma_f32_16x16x32_bf16(bfr[nt * 2 + 1], a1, acc, 0, 0, 0);
      float s = ssv[nt];
      uint2 pw;
      pw.x = pk(acc[0] * s, acc[1] * s);
      pw.y = pk(acc[2] * s, acc[3] * s);
      *(uint2*)&rwt[c16][nt * 16 + quad * 4] = pw;   // 8B aligned (264B rows)
    }
    asm volatile("s_waitcnt lgkmcnt(0)" ::: "memory");   // same-wave LDS w->r
    // ---- aggregation: pure LDS + VALU
    int emax = min(16, dj - kbase);
    for (int e = 0; e < emax; ++e) {
      uint4 q = *(const uint4*)&ysh[e][kh * 8];
      uint2 rp = *(const uint2*)&rwt[e][cA * 4];
      float r0 = lo16(rp.x), r1 = hi16(rp.x), r2v = lo16(rp.y), r3 = hi16(rp.y);
      // L_OF_LM: kh0 -> l={0,1,1,1,2,2,2,2}; kh1 -> l={2,3,3,3,3,3,3,3}
      float w0 = kh ? r2v : r0, w13 = kh ? r3 : r1, w47 = kh ? r3 : r2v;
      acc0 = fmaf(w0,  lo16(q.x), acc0);
      acc1 = fmaf(w13, hi16(q.x), acc1);
      acc2 = fmaf(w13, lo16(q.y), acc2);
      acc3 = fmaf(w13, hi16(q.y), acc3);
      acc4 = fmaf(w47, lo16(q.z), acc4);
      acc5 = fmaf(w47, hi16(q.z), acc5);
      acc6 = fmaf(w47, lo16(q.w), acc6);
      acc7 = fmaf(w47, hi16(q.w), acc7);
    }
  }
  __syncthreads();   // all waves done with w2t/bfr region -> reuse for lagg/lf

  const float invavg = 1.0f / 16.0f;
  lagg[w][cA][kb + 0] = acc0 * invavg;
  lagg[w][cA][kb + 1] = acc1 * invavg;
  lagg[w][cA][kb + 2] = acc2 * invavg;
  lagg[w][cA][kb + 3] = acc3 * invavg;
  lagg[w][cA][kb + 4] = acc4 * invavg;
  lagg[w][cA][kb + 5] = acc5 * invavg;
  lagg[w][cA][kb + 6] = acc6 * invavg;
  lagg[w][cA][kb + 7] = acc7 * invavg;
  __syncthreads();

  // ---- mix + poly + skip + scal_out + lf
  int d = cA;
  int n = n0 + w;
  float ft[8] = {0, 0, 0, 0, 0, 0, 0, 0};
  const float* Wm = W_mix + layer * 4096;
  for (int cc2 = 0; cc2 < CC; ++cc2) {
    float m0 = Wm[cc2 * CC + d];
    float m1 = Wm[1024 + cc2 * CC + d];
    float m2 = Wm[2048 + cc2 * CC + d];
    float m3 = Wm[3072 + cc2 * CC + d];
    float u0 = kh ? m2 : m0;
    float u13 = kh ? m3 : m1;
    float u47 = kh ? m3 : m2;
    ft[0] = fmaf(lagg[w][cc2][kb + 0], u0, ft[0]);
    ft[1] = fmaf(lagg[w][cc2][kb + 1], u13, ft[1]);
    ft[2] = fmaf(lagg[w][cc2][kb + 2], u13, ft[2]);
    ft[3] = fmaf(lagg[w][cc2][kb + 3], u13, ft[3]);
    ft[4] = fmaf(lagg[w][cc2][kb + 4], u47, ft[4]);
    ft[5] = fmaf(lagg[w][cc2][kb + 5], u47, ft[5]);
    ft[6] = fmaf(lagg[w][cc2][kb + 6], u47, ft[6]);
    ft[7] = fmaf(lagg[w][cc2][kb + 7], u47, ft[7]);
  }
  float sv = __shfl(ft[0], lane & 62, 64);   // k=0 pre-poly from even lane of pair
  const float* Wp = W_prod + layer * 96;
  float p0 = Wp[d], p1 = Wp[32 + d], p2 = Wp[64 + d];
  float poly = fmaf(fmaf(p2, sv, p1), sv, p0);
#pragma unroll
  for (int j = 0; j < 8; ++j) ft[j] *= poly;
  if (layer == 0 && kh == 0) ft[0] += sc_skip[n * CC + d];
  if (kh == 0) {
    scal_out[n * CC + d] = ft[0];
    lf[w][d][0] = ft[0]; lf[w][d][1] = ft[1]; lf[w][d][2] = ft[2]; lf[w][d][3] = ft[3];
  }
  __syncthreads();
  if (lane < 13) {
    float sum = 0.0f;
    if (lane < 10) {
      const float* Wr = W_ro_s + layer * CC * NEL;
      for (int dd = 0; dd < CC; ++dd) sum = fmaf(lf[w][dd][0], Wr[dd * NEL + lane], sum);
    } else {
      int mm = lane - 10;
      const float* Wv = W_ro_v + layer * CC;
      for (int dd = 0; dd < CC; ++dd) sum = fmaf(lf[w][dd][1 + mm], Wv[dd], sum);
    }
    pred[n * 13 + lane] += sum;
  }
}

// ---------------- K4: loss accumulation + final (last-block ticket) ----------
__global__ __launch_bounds__(256) void k_loss(const float* __restrict__ pred,
    const float* __restrict__ eps, const int* __restrict__ batch,
    float* __restrict__ lnum, float* __restrict__ lcnt,
    int* __restrict__ ticket, float* __restrict__ out, int nblocks)
{
  __shared__ float psum[GG];
  __shared__ int pcnt[GG];
  __shared__ int lastflag;
  int tid = threadIdx.x;
  if (tid < GG) { psum[tid] = 0.0f; pcnt[tid] = 0; }
  __syncthreads();
  int n = blockIdx.x * 256 + tid;
  if (n < NN) {
    int g = batch[n];
    float sum = 0.0f;
#pragma unroll
    for (int j = 0; j < 13; ++j) {
      float dlt = pred[n * 13 + j] - eps[n * 13 + j];
      sum = fmaf(dlt, dlt, sum);
    }
    atomicAdd(&psum[g], sum);
    atomicAdd(&pcnt[g], 1);
  }
  __syncthreads();
  if (tid < GG && pcnt[tid] > 0) {
    atomicAdd(&lnum[tid], psum[tid]);
    atomicAdd(&lcnt[tid], (float)pcnt[tid]);
  }
  __syncthreads();
  if (tid == 0) {
    __threadfence();
    int t = atomicAdd(ticket, 1);
    lastflag = (t == nblocks - 1) ? 1 : 0;
  }
  __syncthreads();
  if (lastflag && tid < GG) {
    float num = atomicAdd(&lnum[tid], 0.0f);   // device-coherent read
    float cnt = atomicAdd(&lcnt[tid], 0.0f);
    out[tid] = 0.5f * num / (fmaxf(cnt, 1.0f) * 13.0f);
  }
}

extern "C" void kernel_launch(void* const* d_in, const int* in_sizes, int n_in,
                              void* d_out, int out_size, void* d_ws, size_t ws_size,
                              hipStream_t stream) {
  const float* positions  = (const float*)d_in[0];
  const float* node_attrs = (const float*)d_in[1];
  const float* shifts     = (const float*)d_in[2];
  const float* eps        = (const float*)d_in[3];
  const float* alpha_bar  = (const float*)d_in[4];
  const float* W_embed    = (const float*)d_in[5];
  const float* W_r1       = (const float*)d_in[6];
  const float* W_r2       = (const float*)d_in[7];
  const float* W_mix      = (const float*)d_in[8];
  const float* W_sc       = (const float*)d_in[9];
  const float* W_prod     = (const float*)d_in[10];
  const float* W_ro_s     = (const float*)d_in[11];
  const float* W_ro_v     = (const float*)d_in[12];
  const int* edge_index   = (const int*)d_in[13];
  const int* batch        = (const int*)d_in[14];
  const int* tarr         = (const int*)d_in[15];
  float* out = (float*)d_out;

  char* ws = (char*)d_ws;
  size_t off = 0;
  auto alloc = [&](size_t bytes) -> void* {
    void* p = ws + off;
    off = (off + bytes + 255) & ~(size_t)255;
    return p;
  };
  // total ~25 MB
  float* pos_noisy = (float*)alloc(NN * 3 * 4);
  float* scalA     = (float*)alloc(NN * CC * 4);
  float* scalB     = (float*)alloc(NN * CC * 4);
  float* sc_skip   = (float*)alloc(NN * CC * 4);
  float* pred      = (float*)alloc(NN * 13 * 4);
  ushort_t* Ys     = (ushort_t*)alloc((size_t)EE * 16 * 2);  // sorted, bf16
  ushort_t* efs    = (ushort_t*)alloc((size_t)EE * 8 * 2);   // sorted, bf16
  int* snds        = (int*)alloc((size_t)EE * 4);            // sorted sender ids
  int* offs        = (int*)alloc((NN + 1) * 4);
  int* cursor      = (int*)alloc(NN * 4);
  float* lnum      = (float*)alloc(GG * 4);
  float* lcnt      = (float*)alloc(GG * 4);
  int* ticket      = (int*)alloc(4);
  (void)ws_size; (void)in_sizes; (void)n_in; (void)out_size;

  const int NB_N = (NN + 255) / 256;   // 79
  const int NB_E = EE / 256;           // 1250
  const int NB_SP = 1 + (NN + 1023) / 1024;  // 21

  k_scanprep<<<NB_SP, 1024, 0, stream>>>(positions, node_attrs, eps, alpha_bar,
                                         W_embed, W_sc, batch, tarr, edge_index,
                                         pos_noisy, scalA, sc_skip, pred,
                                         offs, cursor, lnum, lcnt, ticket);
  k_edge2<<<NB_E, 256, 0, stream>>>(pos_noisy, shifts, edge_index, cursor, Ys, efs, snds);

  for (int layer = 0; layer < 2; ++layer) {
    const float* sin_p = (layer == 0) ? scalA : scalB;
    float* sout_p      = (layer == 0) ? scalB : scalA;
    k_flay<<<NN / NPB, 256, 0, stream>>>(efs, Ys, snds, offs, W_r1, W_r2,
                                         sin_p, sout_p, W_mix, W_prod,
                                         W_ro_s, W_ro_v, sc_skip, pred, layer);
  }

  k_loss<<<NB_N, 256, 0, stream>>>(pred, eps, batch, lnum, lcnt, ticket, out, NB_N);
}

// Round 11
// 354.810 us; speedup vs baseline: 1.2161x; 1.2161x over previous
//
#include <hip/hip_runtime.h>

typedef unsigned short ushort_t;
typedef unsigned int uint_t;

#define NN 20000
#define EE 320000
#define CC 32
#define NEL 10
#define GG 64
#define TTT 1000
#define NBB 8
#define HIDD 64
#define EPB 128         // edges per block in k_rw2 (EE = 2500*128)

typedef __attribute__((ext_vector_type(8))) short bf16x8;
typedef __attribute__((ext_vector_type(4))) float f32x4;

__device__ __forceinline__ float bits2f(uint_t b) { union { uint_t u; float f; } v; v.u = b; return v.f; }
__device__ __forceinline__ ushort_t f2b(float f) {
  union { float f; uint_t u; } v; v.f = f;
  uint_t r = (v.u + 0x7fffu + ((v.u >> 16) & 1u)) >> 16;
  return (ushort_t)r;
}
__device__ __forceinline__ uint_t pk(float a, float b) {
  return (uint_t)f2b(a) | ((uint_t)f2b(b) << 16);
}
__device__ __forceinline__ float lo16(uint_t u) { return bits2f(u << 16); }
__device__ __forceinline__ float hi16(uint_t u) { return bits2f(u & 0xffff0000u); }

// ---------------- K1: node prep (also zeroes deg) ----------------
__global__ __launch_bounds__(256) void k_prep(
    const float* __restrict__ positions, const float* __restrict__ node_attrs,
    const float* __restrict__ eps, const float* __restrict__ alpha_bar,
    const float* __restrict__ W_embed, const float* __restrict__ W_sc,
    const int* __restrict__ batch, const int* __restrict__ tarr,
    float* __restrict__ pos_noisy, float* __restrict__ scalA,
    float* __restrict__ sc_skip, float* __restrict__ pred, int* __restrict__ deg)
{
  int n = blockIdx.x * 256 + threadIdx.x;
  if (n >= NN) return;
  deg[n] = 0;
  int g = batch[n];
  int tn = tarr[g];
  float ab = alpha_bar[tn];
  float sa = sqrtf(ab), sb = sqrtf(fmaxf(1.0f - ab, 0.0f));
#pragma unroll
  for (int j = 0; j < 3; ++j)
    pos_noisy[n * 3 + j] = sa * positions[n * 3 + j] + sb * eps[n * 13 + 10 + j];
  float an[10];
#pragma unroll
  for (int j = 0; j < 10; ++j)
    an[j] = sa * 0.25f * node_attrs[n * 10 + j] + sb * eps[n * 13 + j];
  float tf = (float)tn * (1.0f / (float)TTT);
  for (int d = 0; d < CC; ++d) {
    float h = tf * W_embed[10 * CC + d];
    float sk = 0.0f;
#pragma unroll
    for (int j = 0; j < 10; ++j) {
      h = fmaf(an[j], W_embed[j * CC + d], h);
      sk = fmaf(an[j], W_sc[j * CC + d], sk);
    }
    scalA[n * CC + d] = h;
    sc_skip[n * CC + d] = sk;
  }
#pragma unroll
  for (int j = 0; j < 13; ++j) pred[n * 13 + j] = 0.0f;
}

// ---------------- K2: receiver histogram (multi-block global atomics) --------
__global__ __launch_bounds__(256) void k_edge_deg(const int* __restrict__ ei,
    int* __restrict__ deg)
{
  int e = blockIdx.x * 256 + threadIdx.x;  // EE = 1250*256 exactly
  atomicAdd(&deg[ei[EE + e]], 1);
}

// ---------------- K3: exclusive scan deg -> offs, cursor; zero accumulators --
__global__ __launch_bounds__(1024) void k_scan(const int* __restrict__ deg,
    int* __restrict__ offs, int* __restrict__ cursor,
    float* __restrict__ lnum, float* __restrict__ lcnt, int* __restrict__ ticket)
{
  __shared__ int wsums[16];
  __shared__ int woffs[16];
  int tid = threadIdx.x, lane = tid & 63, wv = tid >> 6;
  if (tid < GG) { lnum[tid] = 0.0f; lcnt[tid] = 0.0f; }
  if (tid == 64) *ticket = 0;
  int base = tid * 20;
  int loc[20];
  int s = 0;
#pragma unroll
  for (int j = 0; j < 20; ++j) {
    int idx = base + j;
    int v = (idx < NN) ? deg[idx] : 0;
    loc[j] = s; s += v;
  }
  int inc = s;
  for (int o = 1; o < 64; o <<= 1) {
    int v = __shfl_up(inc, o, 64);
    if (lane >= o) inc += v;
  }
  if (lane == 63) wsums[wv] = inc;
  __syncthreads();
  if (wv == 0 && lane < 16) {
    int v = wsums[lane];
    int i2 = v;
    for (int o = 1; o < 16; o <<= 1) {
      int vv = __shfl_up(i2, o, 16);
      if (lane >= o) i2 += vv;
    }
    woffs[lane] = i2 - v;
  }
  __syncthreads();
  int texcl = woffs[wv] + (inc - s);
#pragma unroll
  for (int j = 0; j < 20; ++j) {
    int idx = base + j;
    if (idx < NN) { int v = texcl + loc[j]; offs[idx] = v; cursor[idx] = v; }
  }
  if (tid == 1023) offs[NN] = EE;
}

// ---------------- K4: edge geometry, written into receiver-sorted slots ------
__global__ __launch_bounds__(256) void k_edge2(
    const float* __restrict__ pos_noisy, const float* __restrict__ shifts,
    const int* __restrict__ ei, int* __restrict__ cursor,
    ushort_t* __restrict__ Ys, ushort_t* __restrict__ efs, int* __restrict__ snds)
{
  int e = blockIdx.x * 256 + threadIdx.x;  // EE exact
  int snd = ei[e], rcv = ei[EE + e];
  float vx = pos_noisy[rcv * 3 + 0] - pos_noisy[snd * 3 + 0] + shifts[e * 3 + 0];
  float vy = pos_noisy[rcv * 3 + 1] - pos_noisy[snd * 3 + 1] + shifts[e * 3 + 1];
  float vz = pos_noisy[rcv * 3 + 2] - pos_noisy[snd * 3 + 2] + shifts[e * 3 + 2];
  float r2 = vx * vx + vy * vy + vz * vz + 1e-12f;
  float r = sqrtf(r2);
  float inv = 1.0f / r;
  float x = vx * inv, y = vy * inv, z = vz * inv;

  const float s3 = 1.7320508075688772f, s15 = 3.872983346207417f, s5 = 2.23606797749979f;
  const float s105 = 10.246950765959598f, s7 = 2.6457513110645907f;
  const float s35_8 = 2.091650066335189f, s21_8 = 1.6201851746019651f;
  float yv[16];
  yv[0] = 1.0f;
  yv[1] = s3 * x; yv[2] = s3 * y; yv[3] = s3 * z;
  yv[4] = s15 * x * y;
  yv[5] = s15 * y * z;
  yv[6] = 0.5f * s5 * (3.0f * z * z - 1.0f);
  yv[7] = s15 * x * z;
  yv[8] = 0.5f * s15 * (x * x - y * y);
  yv[9] = s35_8 * y * (3.0f * x * x - y * y);
  yv[10] = s105 * x * y * z;
  yv[11] = s21_8 * y * (5.0f * z * z - 1.0f);
  yv[12] = 0.5f * s7 * (5.0f * z * z * z - 3.0f * z);
  yv[13] = s21_8 * x * (5.0f * z * z - 1.0f);
  yv[14] = 0.5f * s105 * z * (x * x - y * y);
  yv[15] = s35_8 * x * (x * x - 3.0f * y * y);

  // radial embed: sqrt(2/5) * sin(n*pi*rc/5)/rc * poly_cutoff(r/5)
  float rc = fmaxf(r, 1e-9f);
  float pref = 0.6324555320336759f / rc;
  float th = 0.6283185307179586f * rc;
  float s1 = __sinf(th), c1 = __cosf(th);
  float xr = r * 0.2f;
  float fcut = 0.0f;
  if (xr < 1.0f) {
    float x2 = xr * xr, x3 = x2 * xr;
    float x6 = x3 * x3, x7 = x6 * xr, x8 = x7 * xr;
    fcut = 1.0f - 28.0f * x6 + 48.0f * x7 - 21.0f * x8;
  }
  float efv[8];
  float sp = 0.0f, scur = s1, c2 = 2.0f * c1;
#pragma unroll
  for (int b = 0; b < 8; ++b) {
    efv[b] = pref * scur * fcut;
    float nx = c2 * scur - sp;   // sin((n+1)th) = 2cos(th)sin(n th) - sin((n-1)th)
    sp = scur; scur = nx;
  }

  int slot = atomicAdd(&cursor[rcv], 1);
  snds[slot] = snd;
  uint4* Y4 = (uint4*)Ys;
  Y4[(size_t)slot * 2 + 0] = make_uint4(pk(yv[0], yv[1]), pk(yv[2], yv[3]),
                                        pk(yv[4], yv[5]), pk(yv[6], yv[7]));
  Y4[(size_t)slot * 2 + 1] = make_uint4(pk(yv[8], yv[9]), pk(yv[10], yv[11]),
                                        pk(yv[12], yv[13]), pk(yv[14], yv[15]));
  ((uint4*)efs)[slot] = make_uint4(pk(efv[0], efv[1]), pk(efv[2], efv[3]),
                                   pk(efv[4], efv[5]), pk(efv[6], efv[7]));
}

// ---------------- K5: edge radial MLP via MFMA (swapped operands) -------------
// A = W2^T frags (m=output col), B = h1 (n=edge) -> D=[col][edge]:
// one uint2 store per n-tile per lane, one sender/ss-base per lane.
__global__ __launch_bounds__(256) void k_rw2(
    const ushort_t* __restrict__ efs, const float* __restrict__ W_r1,
    const float* __restrict__ W_r2, const int* __restrict__ snds,
    const float* __restrict__ scal_in, ushort_t* __restrict__ rwc, int layer)
{
  __shared__ __align__(16) ushort_t w2t[128][72];   // W2^T bf16 (18.4 KB)
  __shared__ __align__(16) ushort_t h1t[EPB][72];   // h1 bf16, edge-major (18.4 KB)
  __shared__ __align__(16) float w1s[NBB * HIDD];   // 2 KB
  int tid = threadIdx.x;
  const float* W1g = W_r1 + layer * NBB * HIDD;
  const float* W2g = W_r2 + layer * HIDD * 128;
  for (int idx = tid; idx < HIDD * 128; idx += 256) {
    int k = idx >> 7, n = idx & 127;
    w2t[n][k] = f2b(W2g[idx]);
  }
  for (int i = tid; i < NBB * HIDD; i += 256) w1s[i] = W1g[i];
  __syncthreads();
  // h1: 2 threads per edge, each computes 32 h-values (w1s reads are broadcast)
  {
    int e = tid & 127, half = tid >> 7;
    uint4 q = ((const uint4*)efs)[(size_t)blockIdx.x * EPB + e];
    float ef8[8] = {lo16(q.x), hi16(q.x), lo16(q.y), hi16(q.y),
                    lo16(q.z), hi16(q.z), lo16(q.w), hi16(q.w)};
    for (int hc = 0; hc < 4; ++hc) {
      float v[8];
#pragma unroll
      for (int hh = 0; hh < 8; ++hh) {
        int h = half * 32 + hc * 8 + hh;
        float t = 0.0f;
#pragma unroll
        for (int b = 0; b < 8; ++b) t = fmaf(ef8[b], w1s[b * HIDD + h], t);
        v[hh] = t / (1.0f + __expf(-t));   // silu
      }
      *(uint4*)&h1t[e][half * 32 + hc * 8] =
          make_uint4(pk(v[0], v[1]), pk(v[2], v[3]), pk(v[4], v[5]), pk(v[6], v[7]));
    }
  }
  __syncthreads();
  int w = tid >> 6, lane = tid & 63;
  int c16 = lane & 15, quad = lane >> 4;
  bf16x8 afr[16];   // A-frags: W2^T rows nt*16+c16
#pragma unroll
  for (int nt = 0; nt < 8; ++nt) {
    afr[nt * 2 + 0] = *(const bf16x8*)&w2t[nt * 16 + c16][quad * 8];
    afr[nt * 2 + 1] = *(const bf16x8*)&w2t[nt * 16 + c16][32 + quad * 8];
  }
#pragma unroll
  for (int mt = 0; mt < 2; ++mt) {
    int mbase = w * 32 + mt * 16;
    bf16x8 b0 = *(const bf16x8*)&h1t[mbase + c16][quad * 8];
    bf16x8 b1 = *(const bf16x8*)&h1t[mbase + c16][32 + quad * 8];
    size_t eg = (size_t)blockIdx.x * EPB + mbase + c16;
    int snd = snds[eg];
    const float* sb = scal_in + (size_t)snd * CC + quad;
    float ssv[8];
#pragma unroll
    for (int nt = 0; nt < 8; ++nt) ssv[nt] = sb[nt * 4];   // chan = 4nt+quad
    uint2* dst = (uint2*)(rwc + eg * 128);
#pragma unroll
    for (int nt = 0; nt < 8; ++nt) {
      f32x4 acc = {0.0f, 0.0f, 0.0f, 0.0f};
      acc = __builtin_amdgcn_mfma_f32_16x16x32_bf16(afr[nt * 2 + 0], b0, acc, 0, 0, 0);
      acc = __builtin_amdgcn_mfma_f32_16x16x32_bf16(afr[nt * 2 + 1], b1, acc, 0, 0, 0);
      float s = ssv[nt];
      dst[nt * 4 + quad] = make_uint2(pk(acc[0] * s, acc[1] * s),
                                      pk(acc[2] * s, acc[3] * s));
    }
  }
}

// ---------------- K6: streaming aggregate + mix + poly + readout --------------
__global__ __launch_bounds__(256) void k_layer(
    const ushort_t* __restrict__ Ys, const ushort_t* __restrict__ rwc,
    float* __restrict__ scal_out,
    const int* __restrict__ offs,
    const float* __restrict__ W_mix, const float* __restrict__ W_prod,
    const float* __restrict__ W_ro_s, const float* __restrict__ W_ro_v,
    const float* __restrict__ sc_skip, float* __restrict__ pred, int layer)
{
  __shared__ float lagg[4][CC][16];
  __shared__ float lf[4][CC][4];
  int w = threadIdx.x >> 6, lane = threadIdx.x & 63;
  int n = blockIdx.x * 4 + w;        // NN = 5000*4 exactly
  int c = lane >> 1;
  int kh = lane & 1;
  int kb = kh * 8;
  int i0 = offs[n], i1 = offs[n + 1];
  float acc0 = 0, acc1 = 0, acc2 = 0, acc3 = 0, acc4 = 0, acc5 = 0, acc6 = 0, acc7 = 0;
  const uint4* Y4 = (const uint4*)Ys;
  const uint2* rw2 = (const uint2*)rwc;
  int s = i0;
  // unroll x4: 8 independent loads in flight before any use
  for (; s + 4 <= i1; s += 4) {
    uint4 q0 = Y4[(size_t)(s + 0) * 2 + kh];
    uint2 p0 = rw2[(size_t)(s + 0) * 32 + c];
    uint4 q1 = Y4[(size_t)(s + 1) * 2 + kh];
    uint2 p1 = rw2[(size_t)(s + 1) * 32 + c];
    uint4 q2 = Y4[(size_t)(s + 2) * 2 + kh];
    uint2 p2 = rw2[(size_t)(s + 2) * 32 + c];
    uint4 q3 = Y4[(size_t)(s + 3) * 2 + kh];
    uint2 p3 = rw2[(size_t)(s + 3) * 32 + c];
#pragma unroll
    for (int u = 0; u < 4; ++u) {
      uint4 q = (u == 0) ? q0 : (u == 1) ? q1 : (u == 2) ? q2 : q3;
      uint2 rp = (u == 0) ? p0 : (u == 1) ? p1 : (u == 2) ? p2 : p3;
      float r0 = lo16(rp.x), r1 = hi16(rp.x), r2v = lo16(rp.y), r3 = hi16(rp.y);
      // L_OF_LM: kh0 -> l={0,1,1,1,2,2,2,2}; kh1 -> l={2,3,3,3,3,3,3,3}
      float w0 = kh ? r2v : r0, w13 = kh ? r3 : r1, w47 = kh ? r3 : r2v;
      acc0 = fmaf(w0,  lo16(q.x), acc0);
      acc1 = fmaf(w13, hi16(q.x), acc1);
      acc2 = fmaf(w13, lo16(q.y), acc2);
      acc3 = fmaf(w13, hi16(q.y), acc3);
      acc4 = fmaf(w47, lo16(q.z), acc4);
      acc5 = fmaf(w47, hi16(q.z), acc5);
      acc6 = fmaf(w47, lo16(q.w), acc6);
      acc7 = fmaf(w47, hi16(q.w), acc7);
    }
  }
  for (; s < i1; ++s) {
    uint4 q = Y4[(size_t)s * 2 + kh];
    uint2 rp = rw2[(size_t)s * 32 + c];
    float r0 = lo16(rp.x), r1 = hi16(rp.x), r2v = lo16(rp.y), r3 = hi16(rp.y);
    float w0 = kh ? r2v : r0, w13 = kh ? r3 : r1, w47 = kh ? r3 : r2v;
    acc0 = fmaf(w0,  lo16(q.x), acc0);
    acc1 = fmaf(w13, hi16(q.x), acc1);
    acc2 = fmaf(w13, lo16(q.y), acc2);
    acc3 = fmaf(w13, hi16(q.y), acc3);
    acc4 = fmaf(w47, lo16(q.z), acc4);
    acc5 = fmaf(w47, hi16(q.z), acc5);
    acc6 = fmaf(w47, lo16(q.w), acc6);
    acc7 = fmaf(w47, hi16(q.w), acc7);
  }
  const float invavg = 1.0f / 16.0f;
  lagg[w][c][kb + 0] = acc0 * invavg;
  lagg[w][c][kb + 1] = acc1 * invavg;
  lagg[w][c][kb + 2] = acc2 * invavg;
  lagg[w][c][kb + 3] = acc3 * invavg;
  lagg[w][c][kb + 4] = acc4 * invavg;
  lagg[w][c][kb + 5] = acc5 * invavg;
  lagg[w][c][kb + 6] = acc6 * invavg;
  lagg[w][c][kb + 7] = acc7 * invavg;
  __syncthreads();
  int d = c;
  float ft[8] = {0, 0, 0, 0, 0, 0, 0, 0};
  const float* Wm = W_mix + layer * 4096;
  for (int cc2 = 0; cc2 < CC; ++cc2) {
    float m0 = Wm[cc2 * CC + d];
    float m1 = Wm[1024 + cc2 * CC + d];
    float m2 = Wm[2048 + cc2 * CC + d];
    float m3 = Wm[3072 + cc2 * CC + d];
    float u0 = kh ? m2 : m0;
    float u13 = kh ? m3 : m1;
    float u47 = kh ? m3 : m2;
    ft[0] = fmaf(lagg[w][cc2][kb + 0], u0, ft[0]);
    ft[1] = fmaf(lagg[w][cc2][kb + 1], u13, ft[1]);
    ft[2] = fmaf(lagg[w][cc2][kb + 2], u13, ft[2]);
    ft[3] = fmaf(lagg[w][cc2][kb + 3], u13, ft[3]);
    ft[4] = fmaf(lagg[w][cc2][kb + 4], u47, ft[4]);
    ft[5] = fmaf(lagg[w][cc2][kb + 5], u47, ft[5]);
    ft[6] = fmaf(lagg[w][cc2][kb + 6], u47, ft[6]);
    ft[7] = fmaf(lagg[w][cc2][kb + 7], u47, ft[7]);
  }
  float sv = __shfl(ft[0], lane & 62, 64);   // k=0 pre-poly from even lane of pair
  const float* Wp = W_prod + layer * 96;
  float p0 = Wp[d], p1 = Wp[32 + d], p2 = Wp[64 + d];
  float poly = fmaf(fmaf(p2, sv, p1), sv, p0);
#pragma unroll
  for (int j = 0; j < 8; ++j) ft[j] *= poly;
  if (layer == 0 && kh == 0) ft[0] += sc_skip[n * CC + d];
  if (kh == 0) {
    scal_out[n * CC + d] = ft[0];
    lf[w][d][0] = ft[0]; lf[w][d][1] = ft[1]; lf[w][d][2] = ft[2]; lf[w][d][3] = ft[3];
  }
  __syncthreads();
  if (lane < 13) {
    float sum = 0.0f;
    if (lane < 10) {
      const float* Wr = W_ro_s + layer * CC * NEL;
      for (int dd = 0; dd < CC; ++dd) sum = fmaf(lf[w][dd][0], Wr[dd * NEL + lane], sum);
    } else {
      int mm = lane - 10;
      const float* Wv = W_ro_v + layer * CC;
      for (int dd = 0; dd < CC; ++dd) sum = fmaf(lf[w][dd][1 + mm], Wv[dd], sum);
    }
    pred[n * 13 + lane] += sum;
  }
}

// ---------------- K7: loss accumulation + final (last-block ticket) ----------
__global__ __launch_bounds__(256) void k_loss(const float* __restrict__ pred,
    const float* __restrict__ eps, const int* __restrict__ batch,
    float* __restrict__ lnum, float* __restrict__ lcnt,
    int* __restrict__ ticket, float* __restrict__ out, int nblocks)
{
  __shared__ float psum[GG];
  __shared__ int pcnt[GG];
  __shared__ int lastflag;
  int tid = threadIdx.x;
  if (tid < GG) { psum[tid] = 0.0f; pcnt[tid] = 0; }
  __syncthreads();
  int n = blockIdx.x * 256 + tid;
  if (n < NN) {
    int g = batch[n];
    float sum = 0.0f;
#pragma unroll
    for (int j = 0; j < 13; ++j) {
      float dlt = pred[n * 13 + j] - eps[n * 13 + j];
      sum = fmaf(dlt, dlt, sum);
    }
    atomicAdd(&psum[g], sum);
    atomicAdd(&pcnt[g], 1);
  }
  __syncthreads();
  if (tid < GG && pcnt[tid] > 0) {
    atomicAdd(&lnum[tid], psum[tid]);
    atomicAdd(&lcnt[tid], (float)pcnt[tid]);
  }
  __syncthreads();
  if (tid == 0) {
    __threadfence();
    int t = atomicAdd(ticket, 1);
    lastflag = (t == nblocks - 1) ? 1 : 0;
  }
  __syncthreads();
  if (lastflag && tid < GG) {
    float num = atomicAdd(&lnum[tid], 0.0f);   // device-coherent read
    float cnt = atomicAdd(&lcnt[tid], 0.0f);
    out[tid] = 0.5f * num / (fmaxf(cnt, 1.0f) * 13.0f);
  }
}

extern "C" void kernel_launch(void* const* d_in, const int* in_sizes, int n_in,
                              void* d_out, int out_size, void* d_ws, size_t ws_size,
                              hipStream_t stream) {
  const float* positions  = (const float*)d_in[0];
  const float* node_attrs = (const float*)d_in[1];
  const float* shifts     = (const float*)d_in[2];
  const float* eps        = (const float*)d_in[3];
  const float* alpha_bar  = (const float*)d_in[4];
  const float* W_embed    = (const float*)d_in[5];
  const float* W_r1       = (const float*)d_in[6];
  const float* W_r2       = (const float*)d_in[7];
  const float* W_mix      = (const float*)d_in[8];
  const float* W_sc       = (const float*)d_in[9];
  const float* W_prod     = (const float*)d_in[10];
  const float* W_ro_s     = (const float*)d_in[11];
  const float* W_ro_v     = (const float*)d_in[12];
  const int* edge_index   = (const int*)d_in[13];
  const int* batch        = (const int*)d_in[14];
  const int* tarr         = (const int*)d_in[15];
  float* out = (float*)d_out;

  char* ws = (char*)d_ws;
  size_t off = 0;
  auto alloc = [&](size_t bytes) -> void* {
    void* p = ws + off;
    off = (off + bytes + 255) & ~(size_t)255;
    return p;
  };
  // total ~107 MB (ws = 256 MiB)
  float* pos_noisy = (float*)alloc(NN * 3 * 4);
  float* scalA     = (float*)alloc(NN * CC * 4);
  float* scalB     = (float*)alloc(NN * CC * 4);
  float* sc_skip   = (float*)alloc(NN * CC * 4);
  float* pred      = (float*)alloc(NN * 13 * 4);
  ushort_t* Ys     = (ushort_t*)alloc((size_t)EE * 16 * 2);  // sorted, bf16
  ushort_t* efs    = (ushort_t*)alloc((size_t)EE * 8 * 2);   // sorted, bf16
  int* snds        = (int*)alloc((size_t)EE * 4);            // sorted sender ids
  ushort_t* rwc    = (ushort_t*)alloc((size_t)EE * 128 * 2); // rw*ss, bf16 (82 MB)
  int* deg         = (int*)alloc(NN * 4);
  int* offs        = (int*)alloc((NN + 1) * 4);
  int* cursor      = (int*)alloc(NN * 4);
  float* lnum      = (float*)alloc(GG * 4);
  float* lcnt      = (float*)alloc(GG * 4);
  int* ticket      = (int*)alloc(4);
  (void)ws_size; (void)in_sizes; (void)n_in; (void)out_size;

  const int NB_N = (NN + 255) / 256;   // 79
  const int NB_E = EE / 256;           // 1250

  k_prep<<<NB_N, 256, 0, stream>>>(positions, node_attrs, eps, alpha_bar, W_embed,
                                   W_sc, batch, tarr, pos_noisy, scalA, sc_skip, pred, deg);
  k_edge_deg<<<NB_E, 256, 0, stream>>>(edge_index, deg);
  k_scan<<<1, 1024, 0, stream>>>(deg, offs, cursor, lnum, lcnt, ticket);
  k_edge2<<<NB_E, 256, 0, stream>>>(pos_noisy, shifts, edge_index, cursor, Ys, efs, snds);

  for (int layer = 0; layer < 2; ++layer) {
    const float* sin_p = (layer == 0) ? scalA : scalB;
    float* sout_p      = (layer == 0) ? scalB : scalA;
    k_rw2<<<EE / EPB, 256, 0, stream>>>(efs, W_r1, W_r2, snds, sin_p, rwc, layer);
    k_layer<<<NN / 4, 256, 0, stream>>>(Ys, rwc, sout_p, offs,
                                        W_mix, W_prod, W_ro_s, W_ro_v,
                                        sc_skip, pred, layer);
  }

  k_loss<<<NB_N, 256, 0, stream>>>(pred, eps, batch, lnum, lcnt, ticket, out, NB_N);
}